// Round 13
// baseline (20.939 us; speedup 1.0000x reference)
//
#include <hip/hip_runtime.h>

#define N 64
#define LC 64
#define LD 32
#define NUNITS 1969             // 16 cont units + 1953 (i,k) pairs
#define NPAIRS 1953

typedef __attribute__((ext_vector_type(8))) short short8;   // 8 bf16 (4 VGPR)
typedef __attribute__((ext_vector_type(4))) float f32x4;

// float -> bf16 bits, round-to-nearest-even
__device__ inline unsigned f2bf(float f) {
    unsigned u = __float_as_uint(f);
    u += 0x7FFF + ((u >> 16) & 1);
    return u >> 16;
}
__device__ inline float bf2f(unsigned u) {
    return __uint_as_float(u << 16);
}

__global__ __launch_bounds__(1024, 4) void loss_kernel(
    const float* __restrict__ cont_w,   // [N,N,LC]
    const float* __restrict__ disc_w,   // [N,N,LD]  ("dw")
    const float* __restrict__ gap_w,    // [N,N,LD]  ("gw")
    const int*   __restrict__ cont_gold,// [N,N] values 0..LC
    const int*   __restrict__ disc_gold,// [T]   values 0..LD
    float* __restrict__ out)
{
    // 4 independent teams of 256 threads; per-team bf16 exp tables.
    __shared__ unsigned short EgB[4][64 * 32];   // exp(gw slab), A operand (l)
    __shared__ unsigned short EdB[4][64 * 32];   // exp(dw slab), B operand (j)
    __shared__ float ws[16];

    const int team  = threadIdx.x >> 8;          // 0..3
    const int tid   = threadIdx.x & 255;         // 0..255 within team
    const int gteam = (int)blockIdx.x * 4 + team;// 0..1023

    float acc = 0.0f;

    #pragma unroll
    for (int rep = 0; rep < 2; ++rep) {
        const int u = gteam + rep * 1024;        // work unit id
        const bool valid   = (u < NUNITS);
        const bool is_cont = valid && (u < 16);
        const bool is_pair = valid && (u >= 16);

        int i = 0, k = 0, M = 0, MT = 0;
        if (is_pair) {
            const int w = u - 16;                // 0..1952
            k = (int)((sqrtf(8.0f * (float)w + 1.0f) - 1.0f) * 0.5f);
            while (k * (k + 1) / 2 > w) --k;
            while ((k + 1) * (k + 2) / 2 <= w) ++k;
            i = w - k * (k + 1) / 2;             // 0..k
            M = 62 - k;
            MT = (M + 15) >> 4;

            // ---- stage: bf16 exp tables, zero-padded to MT*16 rows ----
            const int MT16 = MT << 4;
            const float4* srcD = reinterpret_cast<const float4*>(
                disc_w + ((i << 6) + (k + 2)) * LD);
            const float4* srcG = reinterpret_cast<const float4*>(
                gap_w + (((k + 1) << 6) + (k + 1)) * LD);
            for (int e = tid; e < MT16 * 8; e += 256) {
                const int r = e >> 3, ch = e & 7;
                unsigned short* pd = &EdB[team][r * 32 + ch * 4];
                unsigned short* pg = &EgB[team][r * 32 + ch * 4];
                if (r < M) {
                    float4 x = srcD[e];
                    float4 y = srcG[e];
                    pd[0] = (unsigned short)f2bf(__expf(x.x));
                    pd[1] = (unsigned short)f2bf(__expf(x.y));
                    pd[2] = (unsigned short)f2bf(__expf(x.z));
                    pd[3] = (unsigned short)f2bf(__expf(x.w));
                    pg[0] = (unsigned short)f2bf(__expf(y.x));
                    pg[1] = (unsigned short)f2bf(__expf(y.y));
                    pg[2] = (unsigned short)f2bf(__expf(y.z));
                    pg[3] = (unsigned short)f2bf(__expf(y.w));
                } else {
                    pd[0] = 0; pd[1] = 0; pd[2] = 0; pd[3] = 0;
                    pg[0] = 0; pg[1] = 0; pg[2] = 0; pg[3] = 0;
                }
            }
        }
        __syncthreads();                          // stage visible (all teams)

        if (is_cont) {
            // ---- continuous part: 256 cells per team, 1/thread ----
            const int idx = u * 256 + tid;        // 0..4095
            const int ii = idx >> 6, jj = idx & 63;
            if (ii <= jj) {
                const float4* p =
                    reinterpret_cast<const float4*>(cont_w + idx * LC);
                const int g = cont_gold[idx];     // 0..LC (LC == null col)
                const float goldv = (g < LC) ? cont_w[idx * LC + g] : 0.0f;
                float s0 = 1.0f, s1 = 0.0f, s2 = 0.0f, s3 = 0.0f;
                #pragma unroll
                for (int q = 0; q < LC / 4; ++q) {
                    float4 x = p[q];
                    s0 += __expf(x.x); s1 += __expf(x.y);
                    s2 += __expf(x.z); s3 += __expf(x.w);
                }
                acc = __logf((s0 + s1) + (s2 + s3)) - goldv;
            }
        } else if (is_pair) {
            // ---- MFMA: S[l][j] = sum_k Eg[l][k]*Ed[j][k], upper-tri ----
            const int ntiles = MT * (MT + 1) / 2;
            const int wid  = tid >> 6;            // wave within team, 0..3
            const int lane = tid & 63;
            const int r16  = lane & 15;
            const int g4   = lane >> 4;
            for (int p = wid; p < ntiles; p += 4) {
                int tr = 0, base = 0;
                while (base + (MT - tr) <= p) { base += MT - tr; ++tr; }
                const int tc = tr + (p - base);
                short8 a = *reinterpret_cast<const short8*>(
                    &EgB[team][(tr * 16 + r16) * 32 + g4 * 8]);
                short8 b = *reinterpret_cast<const short8*>(
                    &EdB[team][(tc * 16 + r16) * 32 + g4 * 8]);
                f32x4 c = {0.0f, 0.0f, 0.0f, 0.0f};
                c = __builtin_amdgcn_mfma_f32_16x16x32_bf16(a, b, c, 0, 0, 0);
                #pragma unroll
                for (int q = 0; q < 4; ++q) {
                    const int l = tr * 16 + g4 * 4 + q;   // D row
                    const int j = tc * 16 + r16;          // D col
                    if (j < M && l <= j)
                        acc += __logf(c[q] + 1.0f);       // +1 = null column
                }
            }

            // ---- gold pass: coalesced disc_gold + bf16 LDS lookups ----
            const int A  = 62 - i;
            const int fA = A * (A + 1) * (A + 2) * (A + 3) / 24;
            const int hA = A * (A + 1) * (A + 2) / 6;
            const int hK = M * (M + 1) * (M + 2) / 6;
            const int t0 = (677040 - fA) + (hA - hK);
            const int cells = M * (M + 1) / 2;

            const int Bc = (cells + 255) >> 8;
            const int c0 = tid * Bc;
            const int c1 = min(c0 + Bc, cells);
            if (c0 < c1) {
                const float twoM1 = (float)(2 * M + 1);
                int l = (int)((twoM1 -
                    sqrtf(twoM1 * twoM1 - 8.0f * (float)c0)) * 0.5f);
                if (l < 0) l = 0;
                if (l > M - 1) l = M - 1;
                while (l * M - l * (l - 1) / 2 > c0) --l;
                while ((l + 1) * M - (l + 1) * l / 2 <= c0) ++l;
                int j = l + (c0 - (l * M - l * (l - 1) / 2));
                for (int c = c0; c < c1; ++c) {
                    const int g = disc_gold[t0 + c];
                    if (g < LD) {
                        const float ed = bf2f(EdB[team][j * 32 + g]);
                        const float eg = bf2f(EgB[team][l * 32 + g]);
                        acc -= __logf(ed * eg);
                    }
                    ++j;
                    if (j >= M) { ++l; j = l; }
                }
            }
        }
        __syncthreads();                          // LDS reuse fence (all teams)
    }

    // ---- block reduction over 16 waves, then ONE atomic per block ----
    #pragma unroll
    for (int off = 32; off > 0; off >>= 1)
        acc += __shfl_down(acc, off, 64);
    if ((threadIdx.x & 63) == 0) ws[threadIdx.x >> 6] = acc;
    __syncthreads();
    if (threadIdx.x == 0) {
        float s = 0.0f;
        #pragma unroll
        for (int q = 0; q < 16; ++q) s += ws[q];
        atomicAdd(out, s);                        // 256 atomics total
    }
}

extern "C" void kernel_launch(void* const* d_in, const int* in_sizes, int n_in,
                              void* d_out, int out_size, void* d_ws, size_t ws_size,
                              hipStream_t stream) {
    const float* cont_w    = (const float*)d_in[0];
    const float* disc_w    = (const float*)d_in[1];
    const float* gap_w     = (const float*)d_in[2];
    const int*   cont_gold = (const int*)d_in[3];
    const int*   disc_gold = (const int*)d_in[4];
    float* out = (float*)d_out;

    hipMemsetAsync(out, 0, sizeof(float), stream);
    loss_kernel<<<256, 1024, 0, stream>>>(cont_w, disc_w, gap_w,
                                          cont_gold, disc_gold, out);
}